// Round 9
// baseline (3067.236 us; speedup 1.0000x reference)
//
#include <hip/hip_runtime.h>
#include <math.h>

#define BATCH 10
#define HID 128
#define OUT 7
#define MAXLEN 2048
#define NG 512
#define NT 512
#define RINGD 256
#define OFF_STATE ((size_t)BATCH * MAXLEN * OUT)

typedef float float2v __attribute__((ext_vector_type(2)));
typedef float float4v __attribute__((ext_vector_type(4)));

__device__ __forceinline__ float sigm_(float x) { return 1.0f / (1.0f + __expf(-x)); }
__device__ __forceinline__ float tanh_(float x) { return 1.0f - 2.0f / (1.0f + __expf(2.0f * x)); }

__device__ __forceinline__ float2v vlo(float4v v) { return __builtin_shufflevector(v, v, 0, 1); }
__device__ __forceinline__ float2v vhi(float4v v) { return __builtin_shufflevector(v, v, 2, 3); }

// guaranteed packed fp32 FMA (2 MACs/instr)
__device__ __forceinline__ void pk_fma(float2v& acc, float2v w, float2v h) {
    asm("v_pk_fma_f32 %0, %1, %2, %0" : "+v"(acc) : "v"(w), "v"(h));
}

// AGPR stash: write once (volatile: must not be dropped), read per step
// (volatile: must NOT be LICM-hoisted -- hoisting recreates the 128-live-VGPR
// pressure that made R19/R22 spill).
__device__ __forceinline__ void awrite(float& slot, float v) {
    asm volatile("v_accvgpr_write_b32 %0, %1" : "=a"(slot) : "v"(v));
}
__device__ __forceinline__ float aread(float slot) {
    float d;
    asm volatile("v_accvgpr_read_b32 %0, %1" : "=v"(d) : "a"(slot));
    return d;
}

// 3-round butterfly over 8-lane group: xor1, xor2, row_half_mirror (=xor4,
// valid because quads are uniform after rounds 1-2).
__device__ __forceinline__ float grp8_sum(float v) {
    v += __int_as_float(__builtin_amdgcn_update_dpp(0, __float_as_int(v), 0xB1, 0xF, 0xF, true));
    v += __int_as_float(__builtin_amdgcn_update_dpp(0, __float_as_int(v), 0x4E, 0xF, 0xF, true));
    v += __int_as_float(__builtin_amdgcn_update_dpp(0, __float_as_int(v), 0x141, 0xF, 0xF, true));
    return v;
}

__global__
__attribute__((amdgpu_flat_work_group_size(NT, NT), amdgpu_waves_per_eu(2, 2)))
void decoder_rnn_kernel(const float* __restrict__ h0,
                        const float* __restrict__ c0,
                        const float* __restrict__ tonehot,   // (MAXLEN+1, 1, OUT)
                        const void*  __restrict__ tf_raw,    // bool mask, int8 or int32
                        const float* __restrict__ Wih,       // (4H, OUT)
                        const float* __restrict__ Whh,       // (4H, H)
                        const float* __restrict__ bih,
                        const float* __restrict__ bhh,
                        const float* __restrict__ Wout,      // (OUT, H)
                        const float* __restrict__ bout,
                        float* __restrict__ out)
{
    // R25: W_hh fully AGPR-resident (the one storage the allocator respects,
    // proven by the base kernel's persistent B-fragments). 128 AGPR/lane
    // written once; per step 128 volatile v_accvgpr_read + 64 v_pk_fma_f32.
    // Geometry = R18: 8 waves; wave w owns gates [w*64,+64); lane
    // (grp=lane>>3, ksl=lane&7) -> 8 gates x 16 K (quads at c*32+ksl*4).
    __shared__ __align__(16) float h_lds[HID];
    __shared__ __align__(16) float gates_lds[NG];
    __shared__ float wih_eff[OUT * NG];              // Wih^T + bias, [x][g]
    __shared__ float ring[RINGD][OUT];               // RAW logits (bout at flush)
    __shared__ unsigned char tgt8[MAXLEN];
    __shared__ unsigned char tf8[MAXLEN];
    __shared__ int tf_byte_mode;

    const int t     = threadIdx.x;
    const int lane  = t & 63;
    const int wv    = t >> 6;         // 0..7
    const int ksl   = lane & 7;       // K sub-slice (4-strided)
    const int grp   = lane >> 3;      // 8-gate group
    const int b     = blockIdx.x;
    const int gbase = wv * 64 + grp * 8;

    // ---- W_hh -> AGPRs: 8 gates x 4 quads = 128 floats per lane ----
    float wa[128];
    #pragma unroll
    for (int g = 0; g < 8; g++)
        #pragma unroll
        for (int c = 0; c < 4; c++) {
            const float4v q = *(const float4v*)&Whh[(size_t)(gbase + g) * HID + c * 32 + ksl * 4];
            #pragma unroll
            for (int e = 0; e < 4; e++)
                awrite(wa[(g * 4 + c) * 4 + e], q[e]);
        }
    // logit weights -> AGPRs (waves 0/1, lane-group grp = logit row; grp=7
    // lanes hold garbage that is never consumed past guarded writes)
    float lwa[16];
    if (wv < 2 && grp < OUT) {
        #pragma unroll
        for (int c = 0; c < 4; c++) {
            const float4v q = *(const float4v*)&Wout[(size_t)grp * HID + c * 32 + ksl * 4];
            #pragma unroll
            for (int e = 0; e < 4; e++)
                awrite(lwa[c * 4 + e], q[e]);
        }
    }

    float boutr[OUT];
    #pragma unroll
    for (int j = 0; j < OUT; j++) boutr[j] = bout[j];

    // ---- LDS setup ----
    for (int idx = t; idx < OUT * NG; idx += NT) {
        int x = idx >> 9, g = idx & (NG - 1);
        wih_eff[idx] = Wih[g * OUT + x] + bih[g] + bhh[g];
    }
    if (t == 0) tf_byte_mode = 0;
    for (int s = t; s < MAXLEN; s += NT) {
        const float* row = tonehot + (size_t)(s + 1) * OUT;
        int idx = 0;
        #pragma unroll
        for (int j = 0; j < OUT; j++) if (row[j] > 0.5f) idx = j;
        tgt8[s] = (unsigned char)idx;
    }
    __syncthreads();
    {   // tf_mask layout detection (int8 bool vs int32) — proven R1-R16
        const unsigned char* tb = (const unsigned char*)tf_raw;
        int mis = 0;
        for (int p = t; p < MAXLEN; p += NT)
            if ((p & 3) && tb[p]) mis = 1;
        if (mis) atomicOr(&tf_byte_mode, 1);
    }
    // ---- state init ----
    float c_reg = 0.f, hv = 0.f;
    if (t < HID) {
        hv    = h0[b * HID + t];
        c_reg = c0[b * HID + t];
        h_lds[t] = hv;
    }
    __syncthreads();
    if (tf_byte_mode) {
        const unsigned char* tb = (const unsigned char*)tf_raw;
        for (int s = t; s < MAXLEN; s += NT) tf8[s] = (tb[s] != 0);
    } else {
        const int* ti = (const int*)tf_raw;
        for (int s = t; s < MAXLEN; s += NT) tf8[s] = (ti[s] != 0);
    }
    __syncthreads();

    float* outlp = out + (size_t)b * MAXLEN * OUT;

    for (int s = 0; s < MAXLEN; s++) {
        // step-control bytes (block-uniform), early
        int tfp = 0, tgp = 0;
        if (s > 0) { tfp = tf8[s - 1]; tgp = tgt8[s - 1]; }

        // tf-step wih prefetch (waves 0/1): xsel known -> hide LDS latency
        float wpre0 = 0.f, wpre1 = 0.f, wpre2 = 0.f, wpre3 = 0.f;
        if (t < HID && tfp) {
            const int xo = tgp * NG;
            wpre0 = wih_eff[xo + t];
            wpre1 = wih_eff[xo + 128 + t];
            wpre2 = wih_eff[xo + 256 + t];
            wpre3 = wih_eff[xo + 384 + t];
        }

        // ---- h quads (8-way broadcast, conflict-free, proven R18) ----
        float4v hc[4];
        #pragma unroll
        for (int c = 0; c < 4; c++)
            hc[c] = *(const float4v*)&h_lds[c * 32 + ksl * 4];

        // ---- matvec: AGPR-fed packed FMA (live temps ~4 by construction) ----
        float a[8];
        #pragma unroll
        for (int g = 0; g < 8; g++) {
            float2v acc = {0.f, 0.f};
            #pragma unroll
            for (int c = 0; c < 4; c++) {
                const int base = (g * 4 + c) * 4;
                float2v wlo, whi;
                wlo[0] = aread(wa[base + 0]);
                wlo[1] = aread(wa[base + 1]);
                whi[0] = aread(wa[base + 2]);
                whi[1] = aread(wa[base + 3]);
                pk_fma(acc, wlo, vlo(hc[c]));
                pk_fma(acc, whi, vhi(hc[c]));
            }
            a[g] = grp8_sum(acc[0] + acc[1]);
        }

        float al = 0.f;
        if (wv < 2) {
            float2v la = {0.f, 0.f};
            #pragma unroll
            for (int c = 0; c < 4; c++) {
                const int base = c * 4;
                float2v wlo, whi;
                wlo[0] = aread(lwa[base + 0]);
                wlo[1] = aread(lwa[base + 1]);
                whi[0] = aread(lwa[base + 2]);
                whi[1] = aread(lwa[base + 3]);
                pk_fma(la, wlo, vlo(hc[c]));
                pk_fma(la, whi, vhi(hc[c]));
            }
            al = grp8_sum(la[0] + la[1]);    // lane holds raw logit[grp]
        }
        if (ksl == 0) {
            float4v g4a, g4b;
            g4a[0] = a[0]; g4a[1] = a[1]; g4a[2] = a[2]; g4a[3] = a[3];
            g4b[0] = a[4]; g4b[1] = a[5]; g4b[2] = a[6]; g4b[3] = a[7];
            *(float4v*)&gates_lds[gbase]     = g4a;
            *(float4v*)&gates_lds[gbase + 4] = g4b;
        }
        __syncthreads();   // A: gates ready; h_lds reads done

        // ---- phase 2a: pointwise (waves 0,1) ----
        if (t < HID) {
            if (s > 0 && wv == 0 && ksl == 0 && grp < OUT)
                ring[(s - 1) & (RINGD - 1)][grp] = al;   // raw logit
            float w0, w1, w2, w3;
            if (tfp) {
                w0 = wpre0; w1 = wpre1; w2 = wpre2; w3 = wpre3;
            } else {
                int xsel = OUT - 1;
                if (s > 0) {
                    float lg[OUT];
                    #pragma unroll
                    for (int j = 0; j < OUT; j++)
                        lg[j] = __int_as_float(__builtin_amdgcn_readlane(__float_as_int(al), 8 * j)) + boutr[j];
                    float bv = lg[0]; int bi = 0;
                    #pragma unroll
                    for (int j = 1; j < OUT; j++) if (lg[j] > bv) { bv = lg[j]; bi = j; }
                    xsel = bi;
                }
                const int xo = xsel * NG;
                w0 = wih_eff[xo + t];
                w1 = wih_eff[xo + 128 + t];
                w2 = wih_eff[xo + 256 + t];
                w3 = wih_eff[xo + 384 + t];
            }
            const float ri = gates_lds[t]           + w0;
            const float rf = gates_lds[HID + t]     + w1;
            const float rg = gates_lds[2 * HID + t] + w2;
            const float ro = gates_lds[3 * HID + t] + w3;
            const float cn = sigm_(rf) * c_reg + sigm_(ri) * tanh_(rg);
            c_reg = cn;
            hv = sigm_(ro) * tanh_(cn);
            h_lds[t] = hv;
        } else if (t >= 256 && t < 384 && (s & 127) == 1 && s > 128) {
            // ---- phase 2b: deferred log-softmax flush (waves 4-5) ----
            const int step = (s - 129) + (t - 256);      // slot-disjoint from (s-1)
            const int slot = step & (RINGD - 1);
            float v[OUT];
            #pragma unroll
            for (int j = 0; j < OUT; j++) v[j] = ring[slot][j] + boutr[j];
            float mx = v[0];
            #pragma unroll
            for (int j = 1; j < OUT; j++) mx = fmaxf(mx, v[j]);
            float sum = 0.f;
            #pragma unroll
            for (int j = 0; j < OUT; j++) sum += __expf(v[j] - mx);
            const float lse = mx + __logf(sum);
            float* dst = outlp + (size_t)step * OUT;
            #pragma unroll
            for (int j = 0; j < OUT; j++) dst[j] = v[j] - lse;
        }
        __syncthreads();   // C: h(s+1) visible
    }

    // ---- epilogue: raw logits for step 2047 from final h ----
    if (wv < 2) {
        float2v la = {0.f, 0.f};
        #pragma unroll
        for (int c = 0; c < 4; c++) {
            const float4v h4 = *(const float4v*)&h_lds[c * 32 + ksl * 4];
            const int base = c * 4;
            float2v wlo, whi;
            wlo[0] = aread(lwa[base + 0]);
            wlo[1] = aread(lwa[base + 1]);
            whi[0] = aread(lwa[base + 2]);
            whi[1] = aread(lwa[base + 3]);
            pk_fma(la, wlo, vlo(h4));
            pk_fma(la, whi, vhi(h4));
        }
        const float al = grp8_sum(la[0] + la[1]);
        if (wv == 0 && ksl == 0 && grp < OUT)
            ring[(MAXLEN - 1) & (RINGD - 1)][grp] = al;
    }
    __syncthreads();
    if (t < 128) {   // final flush: steps 1920..2047 (regular flush covered <1920)
        const int step = (MAXLEN - 128) + t;
        const int slot = step & (RINGD - 1);
        float v[OUT];
        #pragma unroll
        for (int j = 0; j < OUT; j++) v[j] = ring[slot][j] + boutr[j];
        float mx = v[0];
        #pragma unroll
        for (int j = 1; j < OUT; j++) mx = fmaxf(mx, v[j]);
        float sum = 0.f;
        #pragma unroll
        for (int j = 0; j < OUT; j++) sum += __expf(v[j] - mx);
        const float lse = mx + __logf(sum);
        float* dst = outlp + (size_t)step * OUT;
        #pragma unroll
        for (int j = 0; j < OUT; j++) dst[j] = v[j] - lse;
    }
    if (t < HID) {
        out[OFF_STATE + b * HID + t] = hv;                        // hT
        out[OFF_STATE + BATCH * HID + b * HID + t] = c_reg;       // cT
    }
}

extern "C" void kernel_launch(void* const* d_in, const int* in_sizes, int n_in,
                              void* d_out, int out_size, void* d_ws, size_t ws_size,
                              hipStream_t stream) {
    const float* h0    = (const float*)d_in[0];
    const float* c0    = (const float*)d_in[1];
    const float* toh   = (const float*)d_in[2];
    const void*  tfm   = (const void*) d_in[3];
    const float* Wih   = (const float*)d_in[4];
    const float* Whh   = (const float*)d_in[5];
    const float* bih   = (const float*)d_in[6];
    const float* bhh   = (const float*)d_in[7];
    const float* Wout  = (const float*)d_in[8];
    const float* bout  = (const float*)d_in[9];
    float* out = (float*)d_out;

    decoder_rnn_kernel<<<dim3(BATCH), dim3(NT), 0, stream>>>(
        h0, c0, toh, tfm, Wih, Whh, bih, bhh, Wout, bout, out);
}